// Round 1
// baseline (388.094 us; speedup 1.0000x reference)
//
#include <hip/hip_runtime.h>
#include <math.h>

#define KNN 16
#define DIM 128
#define BQ 256
#define NDB 100000
#define NQPRE 4096
#define CH 196
#define NBLK 511                 // ceil(100000/196)
#define CAND_PER_Q (NBLK * KNN)  // 8176
#define TAU_INV 10.0f
#define EPSC 1e-8f
#define FBIG 3.402823e38f

// ---------------- Kernel A: Tq = q_batch @ W, qq = rowsumsq(Tq) ----------------
__global__ void k_tq(const float* __restrict__ qb, const float* __restrict__ W,
                     float* __restrict__ Tq, float* __restrict__ qq) {
    int b = blockIdx.x, c = threadIdx.x;   // block per query row, 128 threads
    __shared__ float qs[DIM];
    qs[c] = qb[b * DIM + c];
    __syncthreads();
    float acc = 0.f;
#pragma unroll 8
    for (int k = 0; k < DIM; ++k) acc = fmaf(qs[k], W[k * DIM + c], acc);
    Tq[b * DIM + c] = acc;
    float s = acc * acc;
#pragma unroll
    for (int m = 32; m >= 1; m >>= 1) s += __shfl_xor(s, m, 64);
    __shared__ float ws2[2];
    if ((c & 63) == 0) ws2[c >> 6] = s;
    __syncthreads();
    if (c == 0) qq[b] = ws2[0] + ws2[1];
}

// ---------------- Kernel B: xsq[j] = ||X[j]||^2 ----------------
__global__ void k_xsq(const float* __restrict__ X, float* __restrict__ xsq) {
    int row = blockIdx.x * 4 + (threadIdx.x >> 6);
    int lane = threadIdx.x & 63;
    if (row >= NDB) return;
    const float2* xr = reinterpret_cast<const float2*>(X + (size_t)row * DIM);
    float2 v = xr[lane];
    float s = fmaf(v.x, v.x, v.y * v.y);
#pragma unroll
    for (int m = 32; m >= 1; m >>= 1) s += __shfl_xor(s, m, 64);
    if (lane == 0) xsq[row] = s;
}

// ---------------- Kernel C: distances + per-(query,chunk) top-16 ----------------
__launch_bounds__(256, 2)
__global__ void k_dist(const float* __restrict__ Tq, const float* __restrict__ qq,
                       const float* __restrict__ X, const float* __restrict__ xsq,
                       float* __restrict__ cand_d, int* __restrict__ cand_i) {
    const int t = threadIdx.x;       // query index (256 queries == blockDim)
    const int blk = blockIdx.x;      // X chunk
    const int j0 = blk * CH;
    const int j1 = (j0 + CH < NDB) ? (j0 + CH) : NDB;

    // own query row in registers (static indexing only)
    float tq[DIM];
    const float4* tqv = reinterpret_cast<const float4*>(Tq + t * DIM);
#pragma unroll
    for (int g = 0; g < DIM / 4; ++g) {
        float4 v = tqv[g];
        tq[4 * g + 0] = v.x; tq[4 * g + 1] = v.y;
        tq[4 * g + 2] = v.z; tq[4 * g + 3] = v.w;
    }
    const float qq_t = qq[t];

    float td[KNN]; int ti[KNN];
#pragma unroll
    for (int i = 0; i < KNN; ++i) { td[i] = FBIG; ti[i] = -1; }

    for (int j = j0; j < j1; ++j) {
        const float4* xr = reinterpret_cast<const float4*>(X + (size_t)j * DIM);
        float a0 = 0.f, a1 = 0.f, a2 = 0.f, a3 = 0.f;
#pragma unroll
        for (int g = 0; g < DIM / 4; ++g) {
            float4 xv = xr[g];   // wave-uniform address -> scalar loads
            a0 = fmaf(xv.x, tq[4 * g + 0], a0);
            a1 = fmaf(xv.y, tq[4 * g + 1], a1);
            a2 = fmaf(xv.z, tq[4 * g + 2], a2);
            a3 = fmaf(xv.w, tq[4 * g + 3], a3);
        }
        float dist = qq_t + xsq[j] - 2.f * ((a0 + a1) + (a2 + a3));
        if (dist < td[KNN - 1]) {   // branchless sorted insertion, fully unrolled
            float d = dist; int id = j;
#pragma unroll
            for (int i = 0; i < KNN; ++i) {
                bool lt = d < td[i];
                float nd = lt ? d : td[i];  int nid = lt ? id : ti[i];
                float od = lt ? td[i] : d;  int oid = lt ? ti[i] : id;
                td[i] = nd; ti[i] = nid; d = od; id = oid;
            }
        }
    }
    size_t base = ((size_t)t * NBLK + blk) * KNN;
#pragma unroll
    for (int i = 0; i < KNN; ++i) { cand_d[base + i] = td[i]; cand_i[base + i] = ti[i]; }
}

// ---------------- Kernel D: per-query merge + exact l2 + softmax + union KL ----------------
__global__ void k_final(const float* __restrict__ Tq, const float* __restrict__ X,
                        const float* __restrict__ cand_d, const int* __restrict__ cand_i,
                        const int* __restrict__ q_indices,
                        const int* __restrict__ pre_indices,
                        const float* __restrict__ pre_weights,
                        float* __restrict__ kl_out) {
    const int q = blockIdx.x, t = threadIdx.x;
    __shared__ float sdA[256 * KNN]; __shared__ int siA[256 * KNN];
    __shared__ float sdB[128 * KNN]; __shared__ int siB[128 * KNN];
    __shared__ int post_idx[KNN];
    __shared__ float l2s[KNN];
    __shared__ float post_w[KNN];
    __shared__ int u_idx[2 * KNN]; __shared__ float u_p[2 * KNN]; __shared__ float u_q[2 * KNN];

    // stage 1: per-thread top-16 over strided candidate slice
    float td[KNN]; int ti[KNN];
#pragma unroll
    for (int i = 0; i < KNN; ++i) { td[i] = FBIG; ti[i] = -1; }
    const float* cd = cand_d + (size_t)q * CAND_PER_Q;
    const int* ci = cand_i + (size_t)q * CAND_PER_Q;
    for (int e = t; e < CAND_PER_Q; e += 256) {
        float dist = cd[e];
        if (dist < td[KNN - 1]) {
            float d = dist; int id = ci[e];
#pragma unroll
            for (int i = 0; i < KNN; ++i) {
                bool lt = d < td[i];
                float nd = lt ? d : td[i];  int nid = lt ? id : ti[i];
                float od = lt ? td[i] : d;  int oid = lt ? ti[i] : id;
                td[i] = nd; ti[i] = nid; d = od; id = oid;
            }
        }
    }
#pragma unroll
    for (int i = 0; i < KNN; ++i) { sdA[t * KNN + i] = td[i]; siA[t * KNN + i] = ti[i]; }

    // stage 2: log2 tree merge of sorted-16 lists
    float* sd = sdA; int* si = siA; float* dd = sdB; int* di = siB;
    int cnt = 256;
    while (cnt > 1) {
        __syncthreads();
        int h = cnt >> 1;
        if (t < h) {
            int i = 0, jj = 0;
#pragma unroll
            for (int o = 0; o < KNN; ++o) {
                float a = (i < KNN) ? sd[t * KNN + i] : FBIG;
                float b2 = (jj < KNN) ? sd[(t + h) * KNN + jj] : FBIG;
                if (a <= b2) { dd[t * KNN + o] = a; di[t * KNN + o] = si[t * KNN + i]; ++i; }
                else         { dd[t * KNN + o] = b2; di[t * KNN + o] = si[(t + h) * KNN + jj]; ++jj; }
            }
        }
        float* tf = sd; sd = dd; dd = tf;
        int* ts = si; si = di; di = ts;
        cnt = h;
    }
    __syncthreads();
    if (t < KNN) post_idx[t] = si[t];
    __syncthreads();

    // stage 3: exact l2 for the 16 selected (16 threads per neighbor, 8 dims each)
    {
        int n = t >> 4, l = t & 15;
        int idx = post_idx[n];
        const float* tr = Tq + q * DIM + l * 8;
        const float* xr = X + (size_t)idx * DIM + l * 8;
        float s = 0.f;
#pragma unroll
        for (int kk = 0; kk < 8; ++kk) { float df = tr[kk] - xr[kk]; s = fmaf(df, df, s); }
#pragma unroll
        for (int m = 1; m < 16; m <<= 1) s += __shfl_xor(s, m, 64);
        if (l == 0) l2s[n] = s;
    }
    __syncthreads();

    if (t == 0) {
        // softmax(-l2/TAU)
        float mx = -FBIG;
        for (int i = 0; i < KNN; ++i) { float v = -l2s[i] * TAU_INV; post_w[i] = v; if (v > mx) mx = v; }
        float sum = 0.f;
        for (int i = 0; i < KNN; ++i) { float e = expf(post_w[i] - mx); post_w[i] = e; sum += e; }
        float inv = 1.f / sum;
        for (int i = 0; i < KNN; ++i) post_w[i] *= inv;

        // union of post (16 distinct) and pre (last-wins on dup) indices
        int qi = q_indices[q];
        int cnt2 = KNN;
        for (int i = 0; i < KNN; ++i) { u_idx[i] = post_idx[i]; u_q[i] = post_w[i]; u_p[i] = 0.f; }
        for (int m = 0; m < KNN; ++m) {
            int pi = pre_indices[qi * KNN + m];
            float pwm = pre_weights[qi * KNN + m];
            int f = -1;
            for (int s2 = 0; s2 < cnt2; ++s2) if (u_idx[s2] == pi) { f = s2; break; }
            if (f >= 0) u_p[f] = pwm;
            else { u_idx[cnt2] = pi; u_p[cnt2] = pwm; u_q[cnt2] = 0.f; ++cnt2; }
        }
        float Zp = 0.f, Zq = 0.f;
        for (int s2 = 0; s2 < cnt2; ++s2) { Zp += fmaxf(u_p[s2], EPSC); Zq += fmaxf(u_q[s2], EPSC); }
        float kl = 0.f;
        float izp = 1.f / Zp, izq = 1.f / Zq;
        for (int s2 = 0; s2 < cnt2; ++s2) {
            float pp = fmaxf(u_p[s2], EPSC) * izp;
            float qv = fmaxf(u_q[s2], EPSC) * izq;
            kl += pp * (logf(pp) - logf(qv));
        }
        kl_out[q] = kl;
    }
}

// ---------------- Kernel E: final reduction + outputs ----------------
__global__ void k_out(const float* __restrict__ kl, const float* __restrict__ W,
                      float* __restrict__ out) {
    int t = threadIdx.x;
    float s_kl = (t < BQ) ? kl[t] : 0.f;
    float s_w = 0.f;
    for (int i = t; i < DIM * DIM; i += 256) { float w = W[i]; s_w = fmaf(w, w, s_w); }
#pragma unroll
    for (int m = 32; m >= 1; m >>= 1) {
        s_kl += __shfl_xor(s_kl, m, 64);
        s_w += __shfl_xor(s_w, m, 64);
    }
    __shared__ float rk[4], rw[4];
    if ((t & 63) == 0) { rk[t >> 6] = s_kl; rw[t >> 6] = s_w; }
    __syncthreads();
    if (t == 0) {
        float kls = rk[0] + rk[1] + rk[2] + rk[3];
        float wss = rw[0] + rw[1] + rw[2] + rw[3];
        float knn = kls * (1.0f / BQ);
        float reg = 0.5f * wss;
        out[0] = 1.0f * knn + 1e-4f * reg;   // BETA*knn + LAMB*reg
        out[1] = 0.f;                         // loss_dist
        out[2] = knn;
    }
}

extern "C" void kernel_launch(void* const* d_in, const int* in_sizes, int n_in,
                              void* d_out, int out_size, void* d_ws, size_t ws_size,
                              hipStream_t stream) {
    const float* q_batch     = (const float*)d_in[0];
    const int*   q_indices   = (const int*)d_in[1];
    const float* X           = (const float*)d_in[2];
    const float* W           = (const float*)d_in[3];
    const int*   pre_indices = (const int*)d_in[4];
    const float* pre_weights = (const float*)d_in[5];

    float* ws = (float*)d_ws;
    float* Tq  = ws;                         // 256*128
    float* qq  = Tq + BQ * DIM;              // 256
    float* xsq = qq + BQ;                    // 100000
    float* klv = xsq + NDB;                  // 256
    float* cand_d = klv + BQ;                // 256*511*16
    int*   cand_i = (int*)(cand_d + (size_t)BQ * NBLK * KNN);

    k_tq<<<dim3(BQ), dim3(DIM), 0, stream>>>(q_batch, W, Tq, qq);
    k_xsq<<<dim3((NDB + 3) / 4), dim3(256), 0, stream>>>(X, xsq);
    k_dist<<<dim3(NBLK), dim3(256), 0, stream>>>(Tq, qq, X, xsq, cand_d, cand_i);
    k_final<<<dim3(BQ), dim3(256), 0, stream>>>(Tq, X, cand_d, cand_i,
                                                q_indices, pre_indices, pre_weights, klv);
    k_out<<<dim3(1), dim3(256), 0, stream>>>(klv, W, (float*)d_out);
}